// Round 2
// baseline (489.573 us; speedup 1.0000x reference)
//
#include <hip/hip_runtime.h>
#include <math.h>

#define EPSV 1e-5

typedef float v4f __attribute__((ext_vector_type(4)));

// d_ws layout:
//   [0  .. 16)            : float2 {new_mean, inv_std}   (written by vn_fold)
//   [16 .. 16 + NBLK*16)  : double2 partials[NBLK]       (NBLK <= 2048)

__global__ __launch_bounds__(256) void vn_partial(
    const float4* __restrict__ xv, const float* __restrict__ xs,
    double2* __restrict__ partials, long long nvec, long long ntail)
{
    // unroll-2 grid-stride: two independent accumulator pairs -> 2x MLP,
    // and the dependent f64-fma chain per accumulator is halved.
    double s0 = 0.0, s20 = 0.0, s1 = 0.0, s21 = 0.0;
    long long tid = (long long)blockIdx.x * blockDim.x + threadIdx.x;
    long long stride = (long long)gridDim.x * blockDim.x;
    long long i = tid;
    for (; i + stride < nvec; i += 2 * stride) {
        float4 va = xv[i];
        float4 vb = xv[i + stride];
        double a0 = (double)va.x, b0 = (double)va.y, c0 = (double)va.z, d0 = (double)va.w;
        double a1 = (double)vb.x, b1 = (double)vb.y, c1 = (double)vb.z, d1 = (double)vb.w;
        s0 += (a0 + b0) + (c0 + d0);
        s20 = fma(a0, a0, s20); s20 = fma(b0, b0, s20);
        s20 = fma(c0, c0, s20); s20 = fma(d0, d0, s20);
        s1 += (a1 + b1) + (c1 + d1);
        s21 = fma(a1, a1, s21); s21 = fma(b1, b1, s21);
        s21 = fma(c1, c1, s21); s21 = fma(d1, d1, s21);
    }
    for (; i < nvec; i += stride) {
        float4 v = xv[i];
        double a = (double)v.x, b = (double)v.y, c = (double)v.z, d = (double)v.w;
        s0 += (a + b) + (c + d);
        s20 = fma(a, a, s20); s20 = fma(b, b, s20);
        s20 = fma(c, c, s20); s20 = fma(d, d, s20);
    }
    if (tid < ntail) {
        double a = (double)xs[nvec * 4 + tid];
        s0 += a;
        s20 = fma(a, a, s20);
    }
    double s = s0 + s1, s2 = s20 + s21;
    // wave (64-lane) reduce
    #pragma unroll
    for (int off = 32; off > 0; off >>= 1) {
        s  += __shfl_down(s, off, 64);
        s2 += __shfl_down(s2, off, 64);
    }
    __shared__ double ls[4][2];
    int lane = threadIdx.x & 63;
    int wv = threadIdx.x >> 6;
    if (lane == 0) { ls[wv][0] = s; ls[wv][1] = s2; }
    __syncthreads();
    if (threadIdx.x == 0) {
        int nw = blockDim.x >> 6;
        double ts = 0.0, t2 = 0.0;
        for (int i2 = 0; i2 < nw; ++i2) { ts += ls[i2][0]; t2 += ls[i2][1]; }
        partials[blockIdx.x] = make_double2(ts, t2);
    }
}

// single block: fold partials once, Chan-merge, publish {mean, inv_std} + scalars
__global__ __launch_bounds__(256) void vn_fold(
    const double2* __restrict__ partials, int nparts,
    const float* __restrict__ cntp, const float* __restrict__ meanp,
    const float* __restrict__ m2p,
    float* __restrict__ out_scalars, float2* __restrict__ nmis, double n)
{
    double s = 0.0, s2 = 0.0;
    for (int i = threadIdx.x; i < nparts; i += blockDim.x) {
        double2 p = partials[i];
        s += p.x; s2 += p.y;
    }
    #pragma unroll
    for (int off = 32; off > 0; off >>= 1) {
        s  += __shfl_down(s, off, 64);
        s2 += __shfl_down(s2, off, 64);
    }
    __shared__ double ls[4][2];
    int lane = threadIdx.x & 63;
    int wv = threadIdx.x >> 6;
    if (lane == 0) { ls[wv][0] = s; ls[wv][1] = s2; }
    __syncthreads();
    if (threadIdx.x == 0) {
        int nw = blockDim.x >> 6;
        double sum = 0.0, sumsq = 0.0;
        for (int i = 0; i < nw; ++i) { sum += ls[i][0]; sumsq += ls[i][1]; }
        double count = (double)*cntp;
        double mean  = (double)*meanp;
        double m2    = (double)*m2p;
        double bmean = sum / n;
        double bm2 = sumsq - n * bmean * bmean;
        if (bm2 < 0.0) bm2 = 0.0;
        double new_count = count + n;
        double delta = bmean - mean;
        double new_mean = mean + delta * n / new_count;
        double new_m2 = m2 + bm2 + delta * delta * count * n / new_count;
        double var = new_m2 / fmax(new_count - 1.0, 1.0);
        double inv_std = 1.0 / sqrt(var + EPSV);
        out_scalars[0] = (float)new_count;
        out_scalars[1] = (float)new_mean;
        out_scalars[2] = (float)new_m2;
        *nmis = make_float2((float)new_mean, (float)inv_std);
    }
}

__global__ __launch_bounds__(256) void vn_norm(
    const float4* __restrict__ xv, const float* __restrict__ xs,
    float4* __restrict__ yv, float* __restrict__ ys,
    const float2* __restrict__ nmis, long long nvec, long long ntail)
{
    // lean prologue: one 8 B load (L2-broadcast), no LDS, no syncthreads
    float2 p = *nmis;
    float nm = p.x;
    float is = p.y;

    // tail elements (ntail == 0 for this shape, kept for generality)
    {
        long long t = (long long)blockIdx.x * blockDim.x + threadIdx.x;
        if (t < ntail) {
            long long j = nvec * 4 + t;
            float r = (xs[j] - nm) * is;
            __builtin_nontemporal_store(r, &ys[j]);
        }
    }

    // Reversed chunk order (x == 256 MiB == L3 size; pass 1 left it resident).
    // Within a chunk lane addressing stays ascending -> coalesced 16 B/lane.
    // Unroll-2 for store/load MLP.
    long long B = blockDim.x;
    long long nchunks = (nvec + B - 1) / B;
    long long gstep = gridDim.x;
    long long t = threadIdx.x;
    long long k = blockIdx.x;
    for (; k + gstep < nchunks; k += 2 * gstep) {
        long long i0 = (nchunks - 1 - k) * B + t;
        long long i1 = (nchunks - 1 - (k + gstep)) * B + t;
        if (i0 < nvec) {
            float4 v = xv[i0];
            v4f o;
            o.x = (v.x - nm) * is;
            o.y = (v.y - nm) * is;
            o.z = (v.z - nm) * is;
            o.w = (v.w - nm) * is;
            __builtin_nontemporal_store(o, (v4f*)&yv[i0]);
        }
        {
            float4 v = xv[i1];
            v4f o;
            o.x = (v.x - nm) * is;
            o.y = (v.y - nm) * is;
            o.z = (v.z - nm) * is;
            o.w = (v.w - nm) * is;
            __builtin_nontemporal_store(o, (v4f*)&yv[i1]);
        }
    }
    for (; k < nchunks; k += gstep) {
        long long i = (nchunks - 1 - k) * B + t;
        if (i < nvec) {
            float4 v = xv[i];
            v4f o;
            o.x = (v.x - nm) * is;
            o.y = (v.y - nm) * is;
            o.z = (v.z - nm) * is;
            o.w = (v.w - nm) * is;
            __builtin_nontemporal_store(o, (v4f*)&yv[i]);
        }
    }
}

extern "C" void kernel_launch(void* const* d_in, const int* in_sizes, int n_in,
                              void* d_out, int out_size, void* d_ws, size_t ws_size,
                              hipStream_t stream) {
    const float* x     = (const float*)d_in[0];
    const float* cntp  = (const float*)d_in[1];
    const float* meanp = (const float*)d_in[2];
    const float* m2p   = (const float*)d_in[3];
    float* out = (float*)d_out;

    long long n = (long long)in_sizes[0];
    long long nvec = n >> 2;
    long long ntail = n & 3;

    float2*  nmis     = (float2*)d_ws;
    double2* partials = (double2*)((char*)d_ws + 16);

    const int threads = 256;
    int blocks = 2048;
    long long need = (nvec + threads - 1) / threads;
    if (need < 1) need = 1;
    if (need < blocks) blocks = (int)need;

    vn_partial<<<blocks, threads, 0, stream>>>((const float4*)x, x, partials, nvec, ntail);
    vn_fold<<<1, threads, 0, stream>>>(partials, blocks, cntp, meanp, m2p,
                                       out + n, nmis, (double)n);
    vn_norm<<<blocks, threads, 0, stream>>>((const float4*)x, x,
                                            (float4*)out, out,
                                            nmis, nvec, ntail);
}

// Round 3
// 478.108 us; speedup vs baseline: 1.0240x; 1.0240x over previous
//
#include <hip/hip_runtime.h>
#include <math.h>

#define EPSV 1e-5

typedef float v4f __attribute__((ext_vector_type(4)));

// d_ws layout: double2 partials[NBLK]  (NBLK = 2048 -> 32 KB)

__global__ __launch_bounds__(256) void vn_partial(
    const float4* __restrict__ xv, const float* __restrict__ xs,
    double2* __restrict__ partials, long long nvec, long long ntail)
{
    double s = 0.0, s2 = 0.0;
    long long tid = (long long)blockIdx.x * blockDim.x + threadIdx.x;
    long long stride = (long long)gridDim.x * blockDim.x;
    for (long long i = tid; i < nvec; i += stride) {
        float4 v = xv[i];
        double a = (double)v.x, b = (double)v.y, c = (double)v.z, d = (double)v.w;
        s += (a + b) + (c + d);
        s2 = fma(a, a, s2);
        s2 = fma(b, b, s2);
        s2 = fma(c, c, s2);
        s2 = fma(d, d, s2);
    }
    if (tid < ntail) {
        double a = (double)xs[nvec * 4 + tid];
        s += a;
        s2 = fma(a, a, s2);
    }
    // wave (64-lane) reduce
    #pragma unroll
    for (int off = 32; off > 0; off >>= 1) {
        s  += __shfl_down(s, off, 64);
        s2 += __shfl_down(s2, off, 64);
    }
    __shared__ double ls[4][2];
    int lane = threadIdx.x & 63;
    int wv = threadIdx.x >> 6;
    if (lane == 0) { ls[wv][0] = s; ls[wv][1] = s2; }
    __syncthreads();
    if (threadIdx.x == 0) {
        int nw = blockDim.x >> 6;
        double ts = 0.0, t2 = 0.0;
        for (int i = 0; i < nw; ++i) { ts += ls[i][0]; t2 += ls[i][1]; }
        partials[blockIdx.x] = make_double2(ts, t2);
    }
}

__global__ __launch_bounds__(256) void vn_norm(
    const float4* __restrict__ xv, const float* __restrict__ xs,
    float4* __restrict__ yv, float* __restrict__ ys,
    const double2* __restrict__ partials, int nparts,
    const float* __restrict__ cntp, const float* __restrict__ meanp,
    const float* __restrict__ m2p,
    float* __restrict__ out_scalars,
    long long nvec, long long ntail, double n)
{
    // every block redundantly folds the partials (L2-broadcast, ~16 KB)
    double s = 0.0, s2 = 0.0;
    for (int i = threadIdx.x; i < nparts; i += blockDim.x) {
        double2 p = partials[i];
        s += p.x; s2 += p.y;
    }
    #pragma unroll
    for (int off = 32; off > 0; off >>= 1) {
        s  += __shfl_down(s, off, 64);
        s2 += __shfl_down(s2, off, 64);
    }
    __shared__ double ls[4][2];
    __shared__ float snm, sis;
    int lane = threadIdx.x & 63;
    int wv = threadIdx.x >> 6;
    if (lane == 0) { ls[wv][0] = s; ls[wv][1] = s2; }
    __syncthreads();
    if (threadIdx.x == 0) {
        int nw = blockDim.x >> 6;
        double sum = 0.0, sumsq = 0.0;
        for (int i = 0; i < nw; ++i) { sum += ls[i][0]; sumsq += ls[i][1]; }
        double count = (double)*cntp;
        double mean  = (double)*meanp;
        double m2    = (double)*m2p;
        double bmean = sum / n;
        double bm2 = sumsq - n * bmean * bmean;
        if (bm2 < 0.0) bm2 = 0.0;
        double new_count = count + n;
        double delta = bmean - mean;
        double new_mean = mean + delta * n / new_count;
        double new_m2 = m2 + bm2 + delta * delta * count * n / new_count;
        double var = new_m2 / fmax(new_count - 1.0, 1.0);
        double inv_std = 1.0 / sqrt(var + EPSV);
        snm = (float)new_mean;
        sis = (float)inv_std;
        if (blockIdx.x == 0) {
            out_scalars[0] = (float)new_count;
            out_scalars[1] = (float)new_mean;
            out_scalars[2] = (float)new_m2;
        }
    }
    __syncthreads();
    float nm = snm;
    float is = sis;

    // Tail elements first (ntail == 0 for this shape, kept for generality).
    {
        long long t = (long long)blockIdx.x * blockDim.x + threadIdx.x;
        if (t < ntail) {
            long long j = nvec * 4 + t;
            float r = (xs[j] - nm) * is;
            __builtin_nontemporal_store(r, &ys[j]);
        }
    }

    // Reversed chunk order (x == 256 MiB == L3 size; pass 1 left it resident).
    // Within a chunk lane addressing stays ascending -> coalesced 16 B/lane.
    long long nchunks = (nvec + blockDim.x - 1) / (long long)blockDim.x;
    for (long long k = blockIdx.x; k < nchunks; k += gridDim.x) {
        long long rk = nchunks - 1 - k;
        long long i = rk * (long long)blockDim.x + threadIdx.x;
        if (i < nvec) {
            float4 v = xv[i];
            v4f o;
            o.x = (v.x - nm) * is;
            o.y = (v.y - nm) * is;
            o.z = (v.z - nm) * is;
            o.w = (v.w - nm) * is;
            // nontemporal: don't let y evict x from Infinity Cache
            __builtin_nontemporal_store(o, (v4f*)&yv[i]);
        }
    }
}

extern "C" void kernel_launch(void* const* d_in, const int* in_sizes, int n_in,
                              void* d_out, int out_size, void* d_ws, size_t ws_size,
                              hipStream_t stream) {
    const float* x     = (const float*)d_in[0];
    const float* cntp  = (const float*)d_in[1];
    const float* meanp = (const float*)d_in[2];
    const float* m2p   = (const float*)d_in[3];
    float* out = (float*)d_out;

    long long n = (long long)in_sizes[0];
    long long nvec = n >> 2;
    long long ntail = n & 3;

    double2* partials = (double2*)d_ws;

    const int threads = 256;
    int blocks = 2048;
    long long need = (nvec + threads - 1) / threads;
    if (need < 1) need = 1;
    if (need < blocks) blocks = (int)need;

    vn_partial<<<blocks, threads, 0, stream>>>((const float4*)x, x, partials, nvec, ntail);
    vn_norm<<<blocks, threads, 0, stream>>>((const float4*)x, x,
                                            (float4*)out, out,
                                            partials, blocks,
                                            cntp, meanp, m2p,
                                            out + n, nvec, ntail, (double)n);
}